// Round 3
// baseline (152.175 us; speedup 1.0000x reference)
//
#include <hip/hip_runtime.h>
#include <hip/hip_bf16.h>
#include <stdint.h>

typedef __bf16 bf16_t;
typedef bf16_t bf16x8 __attribute__((ext_vector_type(8)));
typedef float f32x4 __attribute__((ext_vector_type(4)));

#define DEVI static __device__ __forceinline__

constexpr int NB = 32, CIN = 256, COUT = 256, KNUM = 6, ET = 3, TDIM = 64, VV = 25;
constexpr int NCOL = NB * TDIM * VV;   // 51200 columns (n,t,w)
constexpr int KD   = KNUM * CIN;       // 1536 contraction dim (k,ci)
constexpr long OUT0 = (long)NB * COUT * TDIM * VV;  // 13107200 (x_sum elems)
constexpr int ACNT = ET * VV * VV;     // 1875 (A copy)

// workspace layout
constexpr size_t GT_BYTES   = (size_t)NCOL * KD * 2;        // g, bf16 [col][kc]
constexpr size_t WP_OFF     = GT_BYTES;
constexpr size_t WP_BYTES   = (size_t)COUT * KD * 2;        // Wp, bf16 [c][kc]
constexpr size_t BIAS_OFF   = WP_OFF + WP_BYTES;
constexpr size_t BIAS_BYTES = (size_t)NB * VV * COUT * 4;   // bias [n][w][c] f32
constexpr size_t WS_NEED    = BIAS_OFF + BIAS_BYTES;

// ---------------- prep: Wp permute + bias table + A copy ----------------
__global__ __launch_bounds__(256) void prep_kernel(
    const float* __restrict__ A, const float* __restrict__ Bm,
    const float* __restrict__ lam_p, const float* __restrict__ W,
    const float* __restrict__ bvec, bf16_t* __restrict__ wp2,
    float* __restrict__ biasmat, float* __restrict__ outA)
{
  int idx = blockIdx.x * 256 + threadIdx.x;
  constexpr int S1 = COUT * KD;             // 393216
  constexpr int S2 = S1 + NB * VV * COUT;   // +204800
  constexpr int S3 = S2 + ACNT;
  if (idx < S1) {
    // Wp2[c][k*256+ci] = W[ci][k*256+c]
    int c = idx / KD;
    int r = idx - c * KD;
    int k = r >> 8, ci = r & 255;
    wp2[idx] = (bf16_t)W[ci * KD + (k << 8) + c];
  } else if (idx < S2) {
    // bias[n][w][c] = sum_k b[k*256+c] * S[n,k,w],  S = col-sum of M (lam folded)
    int j = idx - S1;
    int c = j & 255;
    int nw = j >> 8;
    int w = nw % VV;
    int n = nw / VV;
    float lam = lam_p[0];
    float s = 0.f;
    for (int k = 0; k < KNUM; ++k) {
      float sk = 0.f;
      if (k < ET) {
        for (int v = 0; v < VV; ++v) sk += A[(k * VV + v) * VV + w];
      } else {
        for (int v = 0; v < VV; ++v) sk += Bm[(((n * ET) + (k - ET)) * VV + v) * VV + w];
        sk *= lam;
      }
      s += bvec[(k << 8) + c] * sk;
    }
    biasmat[j] = s;
  } else if (idx < S3) {
    int j = idx - S2;
    outA[j] = A[j];   // second tuple output: A passthrough
  }
}

// ---------------- aggregate-first: g[col][kc] = sum_v x*M ----------------
// 4 t-values per thread; 2 k's per block (k-split x3 for occupancy).
// __launch_bounds__(256,2): allow ~256 VGPR so xv[25] f32x4 stays in VGPRs
// (R2 showed VGPR_Count=64 -> accvgpr shuffling doubled VALU ops).
__global__ __launch_bounds__(256, 2) void agg_kernel(
    const float* __restrict__ x, const float* __restrict__ A,
    const float* __restrict__ Bm, const float* __restrict__ lam_p,
    bf16_t* __restrict__ gt)
{
  __shared__ __align__(16) float Mt[2][VV][28];   // [kk][w][v], padded to 28
  const int b = blockIdx.x;           // kp*512 + n*16 + tg
  const int kp = b >> 9;              // 0..2
  const int nt = b & 511;
  const int n = nt >> 4, t0 = (nt & 15) << 2;
  const int k0 = kp << 1;
  const int tid = threadIdx.x;        // tid == ci
  const float lam = lam_p[0];

  for (int i = tid; i < 2 * VV * VV; i += 256) {
    int kk = i / (VV * VV);
    int r = i - kk * VV * VV;
    int v = r / VV;
    int w = r - v * VV;
    int k = k0 + kk;
    float val = (k < ET) ? A[(k * VV + v) * VV + w]
                         : lam * Bm[(((n * ET) + (k - ET)) * VV + v) * VV + w];
    Mt[kk][w][v] = val;               // transpose v<->w for contiguous v reads
  }

  // 100 contiguous floats: x[n, ci, t0..t0+3, 0..24], 16B-aligned (t0%4==0)
  f32x4 xv[25];
  const f32x4* xp4 = (const f32x4*)(x + (((long)(n * CIN + tid) * TDIM + t0) * VV));
  #pragma unroll
  for (int q = 0; q < 25; ++q) xv[q] = xp4[q];
  __syncthreads();

  const long colbase = (long)(n * TDIM + t0) * VV;
  #pragma unroll 1
  for (int kk = 0; kk < 2; ++kk) {
    bf16_t* gk = gt + colbase * KD + ((k0 + kk) << 8) + tid;
    #pragma unroll 1
    for (int w = 0; w < VV; ++w) {
      const f32x4* m4 = (const f32x4*)&Mt[kk][w][0];
      f32x4 m[7];
      #pragma unroll
      for (int q = 0; q < 7; ++q) m[q] = m4[q];   // m[6] tail lanes unused
      float a0 = 0.f, a1 = 0.f, a2 = 0.f, a3 = 0.f;
      #pragma unroll
      for (int v = 0; v < VV; ++v) {
        float mv = m[v >> 2][v & 3];
        a0 += xv[v >> 2][v & 3] * mv;
        a1 += xv[(25 + v) >> 2][(25 + v) & 3] * mv;
        a2 += xv[(50 + v) >> 2][(50 + v) & 3] * mv;
        a3 += xv[(75 + v) >> 2][(75 + v) & 3] * mv;
      }
      bf16_t* gw = gk + (long)w * KD;
      gw[0]            = (bf16_t)a0;
      gw[25 * KD]      = (bf16_t)a1;
      gw[50 * KD]      = (bf16_t)a2;
      gw[75 * KD]      = (bf16_t)a3;
    }
  }
}

// ---------------- MFMA GEMM: out = Wp^T(256x1536) @ g(1536x51200) ----------------
DEVI void gload16(const void* g, void* l) {
  __builtin_amdgcn_global_load_lds((const __attribute__((address_space(1))) void*)g,
                                   (__attribute__((address_space(3))) void*)l, 16, 0, 0);
}

__global__ __launch_bounds__(512) void gemm_kernel(
    const bf16_t* __restrict__ wp2, const bf16_t* __restrict__ gt,
    const float* __restrict__ biasmat, float* __restrict__ out)
{
  // BM=256 (all of c), BN=128 (cols), BK=64. 8 waves in 4(M)x2(N), 64x64 each.
  __shared__ bf16_t As[256 * 64];   // [m][kk] row-major, K-contiguous
  __shared__ bf16_t Bs[128 * 64];   // [nl][kk]
  const int tid = threadIdx.x;
  const int wv = tid >> 6, ln = tid & 63;
  const int col0 = blockIdx.x * 128;
  const int m_base = (wv >> 1) * 64;
  const int n_base = (wv & 1) * 64;

  f32x4 acc[4][4] = {};

  const int itemA0 = wv * 256 + ln;   // +q*64, q<4  (32KB As)
  const int itemB0 = wv * 128 + ln;   // +q*64, q<2  (16KB Bs)

  for (int k0 = 0; k0 < KD; k0 += 64) {
    #pragma unroll
    for (int q = 0; q < 4; ++q) {
      int it = itemA0 + q * 64;
      gload16(wp2 + ((it >> 3) * KD + k0 + (it & 7) * 8), As + it * 8);
    }
    #pragma unroll
    for (int q = 0; q < 2; ++q) {
      int it = itemB0 + q * 64;
      gload16(gt + ((long)(col0 + (it >> 3)) * KD + k0 + (it & 7) * 8), Bs + it * 8);
    }
    __syncthreads();   // drains vmcnt(0) -> tiles visible

    #pragma unroll
    for (int kk = 0; kk < 2; ++kk) {
      const int ko = ((ln >> 4) << 3) + kk * 32;
      bf16x8 af[4], bfr[4];
      #pragma unroll
      for (int i = 0; i < 4; ++i)
        af[i] = *(const bf16x8*)&As[(m_base + i * 16 + (ln & 15)) * 64 + ko];
      #pragma unroll
      for (int j = 0; j < 4; ++j)
        bfr[j] = *(const bf16x8*)&Bs[(n_base + j * 16 + (ln & 15)) * 64 + ko];
      #pragma unroll
      for (int i = 0; i < 4; ++i)
        #pragma unroll
        for (int j = 0; j < 4; ++j)
          acc[i][j] = __builtin_amdgcn_mfma_f32_16x16x32_bf16(af[i], bfr[j], acc[i][j], 0, 0, 0);
    }
    __syncthreads();   // all waves done reading before next stage overwrites
  }

  // epilogue: C/D map col=lane&15, row=(lane>>4)*4+reg  [m89-verified]
  #pragma unroll
  for (int j = 0; j < 4; ++j) {
    int col = col0 + n_base + j * 16 + (ln & 15);
    int n = col / 1600;           // 1600 = T*V
    int tw = col - n * 1600;
    int w = tw % 25;
    float* ob = out + (long)n * 409600 + tw;          // 409600 = 256*1600
    const float* brow = biasmat + (n * 25 + w) * 256;
    #pragma unroll
    for (int i = 0; i < 4; ++i) {
      int mb = m_base + i * 16 + ((ln >> 4) << 2);
      #pragma unroll
      for (int r = 0; r < 4; ++r) {
        int m = mb + r;
        ob[(long)m * 1600] = acc[i][j][r] + brow[m];
      }
    }
  }
}

// ---------------- ws-free fp32 fallback (insurance) ----------------
__global__ __launch_bounds__(256) void fallback_kernel(
    const float* __restrict__ x, const float* __restrict__ A,
    const float* __restrict__ Bm, const float* __restrict__ lam_p,
    const float* __restrict__ W, const float* __restrict__ bvec,
    float* __restrict__ out)
{
  __shared__ __align__(16) float xs[CIN][28];
  __shared__ __align__(16) float Ms[KNUM][VV][28];   // [k][v][w] padded
  const int nt = blockIdx.x;
  const int n = nt >> 6, t = nt & 63;
  const int tid = threadIdx.x;
  const float lam = lam_p[0];

  const float* xp = x + (((long)(n * CIN + tid) * TDIM + t) * VV);
  #pragma unroll
  for (int v = 0; v < VV; ++v) xs[tid][v] = xp[v];
  xs[tid][25] = xs[tid][26] = xs[tid][27] = 0.f;
  for (int i = tid; i < KNUM * VV * VV; i += 256) {
    int k = i / (VV * VV);
    int r = i - k * VV * VV;
    int v = r / VV;
    int w = r - v * VV;
    Ms[k][v][w] = (k < ET) ? A[(k * VV + v) * VV + w]
                           : lam * Bm[(((n * ET) + (k - ET)) * VV + v) * VV + w];
    if (w == 24) { Ms[k][v][25] = Ms[k][v][26] = Ms[k][v][27] = 0.f; }
  }
  __syncthreads();

  float oacc[28] = {};
  for (int k = 0; k < KNUM; ++k) {
    float yv[28];
    float bv = bvec[(k << 8) + tid];
    #pragma unroll
    for (int v = 0; v < 28; ++v) yv[v] = 0.f;
    for (int ci = 0; ci < CIN; ++ci) {
      float wl = W[ci * KD + (k << 8) + tid];
      const f32x4* x4 = (const f32x4*)&xs[ci][0];
      #pragma unroll
      for (int q = 0; q < 7; ++q) {
        f32x4 xv = x4[q];
        yv[q*4+0] += wl*xv[0]; yv[q*4+1] += wl*xv[1];
        yv[q*4+2] += wl*xv[2]; yv[q*4+3] += wl*xv[3];
      }
    }
    #pragma unroll
    for (int v = 0; v < VV; ++v) {
      float yvv = yv[v] + bv;
      const f32x4* m4 = (const f32x4*)&Ms[k][v][0];
      #pragma unroll
      for (int q = 0; q < 7; ++q) {
        f32x4 mv = m4[q];
        oacc[q*4+0] += yvv*mv[0]; oacc[q*4+1] += yvv*mv[1];
        oacc[q*4+2] += yvv*mv[2]; oacc[q*4+3] += yvv*mv[3];
      }
    }
  }
  float* op = out + (((long)(n * COUT + tid) * TDIM + t) * VV);
  #pragma unroll
  for (int w = 0; w < VV; ++w) op[w] = oacc[w];
}

__global__ void copyA_kernel(const float* __restrict__ A, float* __restrict__ outA) {
  int i = blockIdx.x * 256 + threadIdx.x;
  if (i < ACNT) outA[i] = A[i];
}

extern "C" void kernel_launch(void* const* d_in, const int* in_sizes, int n_in,
                              void* d_out, int out_size, void* d_ws, size_t ws_size,
                              hipStream_t stream) {
  const float* x   = (const float*)d_in[0];
  const float* A   = (const float*)d_in[1];
  const float* Bm  = (const float*)d_in[2];
  const float* lam = (const float*)d_in[3];
  const float* W   = (const float*)d_in[4];
  const float* bv  = (const float*)d_in[5];
  float* out = (float*)d_out;

  if (d_ws != nullptr && ws_size >= WS_NEED) {
    bf16_t* gt      = (bf16_t*)d_ws;
    bf16_t* wp2     = (bf16_t*)((char*)d_ws + WP_OFF);
    float*  biasmat = (float*)((char*)d_ws + BIAS_OFF);
    constexpr int PREP_ITEMS = COUT * KD + NB * VV * COUT + ACNT;
    prep_kernel<<<(PREP_ITEMS + 255) / 256, 256, 0, stream>>>(A, Bm, lam, W, bv, wp2, biasmat, out + OUT0);
    agg_kernel<<<3 * NB * TDIM / 4, 256, 0, stream>>>(x, A, Bm, lam, gt);
    gemm_kernel<<<NCOL / 128, 512, 0, stream>>>(wp2, gt, biasmat, out);
  } else {
    fallback_kernel<<<NB * TDIM, 256, 0, stream>>>(x, A, Bm, lam, W, bv, out);
    copyA_kernel<<<(ACNT + 255) / 256, 256, 0, stream>>>(A, out + OUT0);
  }
}

// Round 4
// 127.569 us; speedup vs baseline: 1.1929x; 1.1929x over previous
//
#include <hip/hip_runtime.h>
#include <hip/hip_bf16.h>
#include <stdint.h>

typedef __bf16 bf16_t;
typedef bf16_t bf16x8 __attribute__((ext_vector_type(8)));
typedef float f32x4 __attribute__((ext_vector_type(4)));

#define DEVI static __device__ __forceinline__

constexpr int NB = 32, CIN = 256, COUT = 256, KNUM = 6, ET = 3, TDIM = 64, VV = 25;
constexpr int NCOL = NB * TDIM * VV;   // 51200 columns (n,t,w)
constexpr int KD   = KNUM * CIN;       // 1536 contraction dim (k,ci)
constexpr long OUT0 = (long)NB * COUT * TDIM * VV;  // 13107200 (x_sum elems)
constexpr int ACNT = ET * VV * VV;     // 1875 (A copy)

// workspace layout
constexpr size_t GT_BYTES   = (size_t)NCOL * KD * 2;        // g, bf16 [col][kc]
constexpr size_t WP_OFF     = GT_BYTES;
constexpr size_t WP_BYTES   = (size_t)COUT * KD * 2;        // Wp, bf16 [c][kc]
constexpr size_t BIAS_OFF   = WP_OFF + WP_BYTES;
constexpr size_t BIAS_BYTES = (size_t)NB * VV * COUT * 4;   // bias [n][w][c] f32
constexpr size_t WS_NEED    = BIAS_OFF + BIAS_BYTES;

DEVI unsigned packbf(float lo, float hi) {
  unsigned short a = __builtin_bit_cast(unsigned short, (bf16_t)lo);
  unsigned short b = __builtin_bit_cast(unsigned short, (bf16_t)hi);
  return ((unsigned)b << 16) | (unsigned)a;
}

// ---------------- prep: Wp permute + bias table + A copy ----------------
__global__ __launch_bounds__(256) void prep_kernel(
    const float* __restrict__ A, const float* __restrict__ Bm,
    const float* __restrict__ lam_p, const float* __restrict__ W,
    const float* __restrict__ bvec, bf16_t* __restrict__ wp2,
    float* __restrict__ biasmat, float* __restrict__ outA)
{
  int idx = blockIdx.x * 256 + threadIdx.x;
  constexpr int S1 = COUT * KD;             // 393216
  constexpr int S2 = S1 + NB * VV * COUT;   // +204800
  constexpr int S3 = S2 + ACNT;
  if (idx < S1) {
    // Wp2[c][k*256+ci] = W[ci][k*256+c]
    int c = idx / KD;
    int r = idx - c * KD;
    int k = r >> 8, ci = r & 255;
    wp2[idx] = (bf16_t)W[ci * KD + (k << 8) + c];
  } else if (idx < S2) {
    // bias[n][w][c] = sum_k b[k*256+c] * S[n,k,w],  S = col-sum of M (lam folded)
    int j = idx - S1;
    int c = j & 255;
    int nw = j >> 8;
    int w = nw % VV;
    int n = nw / VV;
    float lam = lam_p[0];
    float s = 0.f;
    for (int k = 0; k < KNUM; ++k) {
      float sk = 0.f;
      if (k < ET) {
        for (int v = 0; v < VV; ++v) sk += A[(k * VV + v) * VV + w];
      } else {
        for (int v = 0; v < VV; ++v) sk += Bm[(((n * ET) + (k - ET)) * VV + v) * VV + w];
        sk *= lam;
      }
      s += bvec[(k << 8) + c] * sk;
    }
    biasmat[j] = s;
  } else if (idx < S3) {
    int j = idx - S2;
    outA[j] = A[j];   // second tuple output: A passthrough
  }
}

// ---------------- MFMA aggregation: g[col][kc] = sum_v x*M ----------------
// Per block: (n, t0..t0+1). A = x rows(ci*2+dt) x v(pad32), B = M[k][w][v].
// D transposed through LDS so gt stores are coalesced 16B/lane.
__global__ __launch_bounds__(256) void agg_kernel(
    const float* __restrict__ x, const float* __restrict__ A,
    const float* __restrict__ Bm, const float* __restrict__ lam_p,
    bf16_t* __restrict__ gt)
{
  __shared__ bf16_t xs[512 * 32];      // [row][v] swizzled 16B groups  (32 KB)
  __shared__ bf16_t Ms[KNUM * 32 * 32];// [k][w][v] zero-padded         (12 KB)
  __shared__ bf16_t dbuf[50 * 264];    // [col=dt*25+w][ci] pad264      (26.4 KB)

  const int b = blockIdx.x;
  const int n = b >> 5;
  const int t0 = (b & 31) << 1;
  const int tid = threadIdx.x;
  const int wid = tid >> 6, ln = tid & 63;
  const float lam = lam_p[0];

  // stage Ms (zero-padded w>=25, v>=25)
  for (int i = tid; i < KNUM * 32 * 32; i += 256) {
    int k = i >> 10, w = (i >> 5) & 31, v = i & 31;
    float val = 0.f;
    if (w < VV && v < VV)
      val = (k < ET) ? A[(k * VV + v) * VV + w]
                     : lam * Bm[(((n * ET) + (k - ET)) * VV + v) * VV + w];
    Ms[i] = (bf16_t)val;
  }

  // stage xs: thread==ci loads x[n,ci,t0+dt,0..24], packs bf16 pairs
  {
    const int ci = tid;
    #pragma unroll
    for (int dt = 0; dt < 2; ++dt) {
      const float* xp = x + ((long)(n * CIN + ci) * TDIM + t0 + dt) * VV;
      float xv[25];
      #pragma unroll
      for (int v = 0; v < VV; ++v) xv[v] = xp[v];
      int row = ci * 2 + dt;
      int sw = (row & 3) ^ ((row >> 2) & 3);
      #pragma unroll
      for (int g = 0; g < 4; ++g) {
        char* base = (char*)xs + row * 64 + ((g ^ sw) & 3) * 16;
        #pragma unroll
        for (int p = 0; p < 4; ++p) {
          int v0 = g * 8 + p * 2;
          float lo = (v0     < VV) ? xv[v0 < VV ? v0 : 0]     : 0.f;
          float hi = (v0 + 1 < VV) ? xv[v0 + 1 < VV ? v0 + 1 : 0] : 0.f;
          *(unsigned*)(base + p * 4) = packbf(lo, hi);
        }
      }
    }
  }
  __syncthreads();

  const f32x4 zero4 = {0.f, 0.f, 0.f, 0.f};
  const int lw = ln & 15, lg = ln >> 4;

  for (int k = 0; k < KNUM; ++k) {
    // B fragments (n-dim = w), k-contiguous reads [verified gemm mapping]
    bf16x8 bfr0 = *(const bf16x8*)&Ms[(k * 32 + lw) * 32 + (lg << 3)];
    bf16x8 bfr1 = *(const bf16x8*)&Ms[(k * 32 + 16 + lw) * 32 + (lg << 3)];
    #pragma unroll
    for (int mt = 0; mt < 8; ++mt) {
      int m0 = (wid * 8 + mt) * 16;
      int row = m0 + lw;
      int sw = (row & 3) ^ ((row >> 2) & 3);
      bf16x8 af = *(const bf16x8*)((const char*)xs + row * 64 + ((lg ^ sw) & 3) * 16);
      f32x4 d0 = __builtin_amdgcn_mfma_f32_16x16x32_bf16(af, bfr0, zero4, 0, 0, 0);
      f32x4 d1 = __builtin_amdgcn_mfma_f32_16x16x32_bf16(af, bfr1, zero4, 0, 0, 0);
      // lane's rows: m0 + 4*lg + r ; r0,r2 -> dt=0 ci0,ci0+1 ; r1,r3 -> dt=1
      int rbase = m0 + (lg << 2);
      int ci0 = rbase >> 1;          // even
      *(unsigned*)((char*)dbuf + (lw)      * 528 + ci0 * 2) = packbf(d0[0], d0[2]);
      *(unsigned*)((char*)dbuf + (25 + lw) * 528 + ci0 * 2) = packbf(d0[1], d0[3]);
      if (lw < 9) {
        *(unsigned*)((char*)dbuf + (16 + lw) * 528 + ci0 * 2) = packbf(d1[0], d1[2]);
        *(unsigned*)((char*)dbuf + (41 + lw) * 528 + ci0 * 2) = packbf(d1[1], d1[3]);
      }
    }
    __syncthreads();
    // store k-slice: 50 cols x 256 ci = 1600 x 16B coalesced
    for (int it = tid; it < 1600; it += 256) {
      int col = it >> 5, cg = it & 31;
      bf16x8 val = *(const bf16x8*)((const char*)dbuf + col * 528 + cg * 16);
      int dt = col / 25, w = col - dt * 25;
      long gaddr = ((long)((n * TDIM + t0 + dt) * VV + w)) * KD + (k << 8) + cg * 8;
      *(bf16x8*)(gt + gaddr) = val;
    }
    __syncthreads();
  }
}

// ---------------- MFMA GEMM: out = Wp^T(256x1536) @ g(1536x51200) ----------------
DEVI void gload16(const void* g, void* l) {
  __builtin_amdgcn_global_load_lds((const __attribute__((address_space(1))) void*)g,
                                   (__attribute__((address_space(3))) void*)l, 16, 0, 0);
}

__global__ __launch_bounds__(512) void gemm_kernel(
    const bf16_t* __restrict__ wp2, const bf16_t* __restrict__ gt,
    const float* __restrict__ biasmat, float* __restrict__ out)
{
  // BM=256 (all of c), BN=128 (cols), BK=64. 8 waves in 4(M)x2(N), 64x64 each.
  __shared__ bf16_t As[256 * 64];   // [m][kk] row-major, K-contiguous
  __shared__ bf16_t Bs[128 * 64];   // [nl][kk]
  const int tid = threadIdx.x;
  const int wv = tid >> 6, ln = tid & 63;
  const int col0 = blockIdx.x * 128;
  const int m_base = (wv >> 1) * 64;
  const int n_base = (wv & 1) * 64;

  f32x4 acc[4][4] = {};

  const int itemA0 = wv * 256 + ln;   // +q*64, q<4  (32KB As)
  const int itemB0 = wv * 128 + ln;   // +q*64, q<2  (16KB Bs)

  for (int k0 = 0; k0 < KD; k0 += 64) {
    #pragma unroll
    for (int q = 0; q < 4; ++q) {
      int it = itemA0 + q * 64;
      gload16(wp2 + ((it >> 3) * KD + k0 + (it & 7) * 8), As + it * 8);
    }
    #pragma unroll
    for (int q = 0; q < 2; ++q) {
      int it = itemB0 + q * 64;
      gload16(gt + ((long)(col0 + (it >> 3)) * KD + k0 + (it & 7) * 8), Bs + it * 8);
    }
    __syncthreads();   // drains vmcnt(0) -> tiles visible

    #pragma unroll
    for (int kk = 0; kk < 2; ++kk) {
      const int ko = ((ln >> 4) << 3) + kk * 32;
      bf16x8 af[4], bfr[4];
      #pragma unroll
      for (int i = 0; i < 4; ++i)
        af[i] = *(const bf16x8*)&As[(m_base + i * 16 + (ln & 15)) * 64 + ko];
      #pragma unroll
      for (int j = 0; j < 4; ++j)
        bfr[j] = *(const bf16x8*)&Bs[(n_base + j * 16 + (ln & 15)) * 64 + ko];
      #pragma unroll
      for (int i = 0; i < 4; ++i)
        #pragma unroll
        for (int j = 0; j < 4; ++j)
          acc[i][j] = __builtin_amdgcn_mfma_f32_16x16x32_bf16(af[i], bfr[j], acc[i][j], 0, 0, 0);
    }
    __syncthreads();   // all waves done reading before next stage overwrites
  }

  // epilogue: C/D map col=lane&15, row=(lane>>4)*4+reg  [m89-verified]
  #pragma unroll
  for (int j = 0; j < 4; ++j) {
    int col = col0 + n_base + j * 16 + (ln & 15);
    int n = col / 1600;           // 1600 = T*V
    int tw = col - n * 1600;
    int w = tw % 25;
    float* ob = out + (long)n * 409600 + tw;          // 409600 = 256*1600
    const float* brow = biasmat + (n * 25 + w) * 256;
    #pragma unroll
    for (int i = 0; i < 4; ++i) {
      int mb = m_base + i * 16 + ((ln >> 4) << 2);
      #pragma unroll
      for (int r = 0; r < 4; ++r) {
        int m = mb + r;
        ob[(long)m * 1600] = acc[i][j][r] + brow[m];
      }
    }
  }
}

// ---------------- ws-free fp32 fallback (insurance) ----------------
__global__ __launch_bounds__(256) void fallback_kernel(
    const float* __restrict__ x, const float* __restrict__ A,
    const float* __restrict__ Bm, const float* __restrict__ lam_p,
    const float* __restrict__ W, const float* __restrict__ bvec,
    float* __restrict__ out)
{
  __shared__ __align__(16) float xs[CIN][28];
  __shared__ __align__(16) float Ms[KNUM][VV][28];   // [k][v][w] padded
  const int nt = blockIdx.x;
  const int n = nt >> 6, t = nt & 63;
  const int tid = threadIdx.x;
  const float lam = lam_p[0];

  const float* xp = x + (((long)(n * CIN + tid) * TDIM + t) * VV);
  #pragma unroll
  for (int v = 0; v < VV; ++v) xs[tid][v] = xp[v];
  xs[tid][25] = xs[tid][26] = xs[tid][27] = 0.f;
  for (int i = tid; i < KNUM * VV * VV; i += 256) {
    int k = i / (VV * VV);
    int r = i - k * VV * VV;
    int v = r / VV;
    int w = r - v * VV;
    Ms[k][v][w] = (k < ET) ? A[(k * VV + v) * VV + w]
                           : lam * Bm[(((n * ET) + (k - ET)) * VV + v) * VV + w];
    if (w == 24) { Ms[k][v][25] = Ms[k][v][26] = Ms[k][v][27] = 0.f; }
  }
  __syncthreads();

  float oacc[28] = {};
  for (int k = 0; k < KNUM; ++k) {
    float yv[28];
    float bv = bvec[(k << 8) + tid];
    #pragma unroll
    for (int v = 0; v < 28; ++v) yv[v] = 0.f;
    for (int ci = 0; ci < CIN; ++ci) {
      float wl = W[ci * KD + (k << 8) + tid];
      const f32x4* x4 = (const f32x4*)&xs[ci][0];
      #pragma unroll
      for (int q = 0; q < 7; ++q) {
        f32x4 xv = x4[q];
        yv[q*4+0] += wl*xv[0]; yv[q*4+1] += wl*xv[1];
        yv[q*4+2] += wl*xv[2]; yv[q*4+3] += wl*xv[3];
      }
    }
    #pragma unroll
    for (int v = 0; v < VV; ++v) {
      float yvv = yv[v] + bv;
      const f32x4* m4 = (const f32x4*)&Ms[k][v][0];
      #pragma unroll
      for (int q = 0; q < 7; ++q) {
        f32x4 mv = m4[q];
        oacc[q*4+0] += yvv*mv[0]; oacc[q*4+1] += yvv*mv[1];
        oacc[q*4+2] += yvv*mv[2]; oacc[q*4+3] += yvv*mv[3];
      }
    }
  }
  float* op = out + (((long)(n * COUT + tid) * TDIM + t) * VV);
  #pragma unroll
  for (int w = 0; w < VV; ++w) op[w] = oacc[w];
}

__global__ void copyA_kernel(const float* __restrict__ A, float* __restrict__ outA) {
  int i = blockIdx.x * 256 + threadIdx.x;
  if (i < ACNT) outA[i] = A[i];
}

extern "C" void kernel_launch(void* const* d_in, const int* in_sizes, int n_in,
                              void* d_out, int out_size, void* d_ws, size_t ws_size,
                              hipStream_t stream) {
  const float* x   = (const float*)d_in[0];
  const float* A   = (const float*)d_in[1];
  const float* Bm  = (const float*)d_in[2];
  const float* lam = (const float*)d_in[3];
  const float* W   = (const float*)d_in[4];
  const float* bv  = (const float*)d_in[5];
  float* out = (float*)d_out;

  if (d_ws != nullptr && ws_size >= WS_NEED) {
    bf16_t* gt      = (bf16_t*)d_ws;
    bf16_t* wp2     = (bf16_t*)((char*)d_ws + WP_OFF);
    float*  biasmat = (float*)((char*)d_ws + BIAS_OFF);
    constexpr int PREP_ITEMS = COUT * KD + NB * VV * COUT + ACNT;
    prep_kernel<<<(PREP_ITEMS + 255) / 256, 256, 0, stream>>>(A, Bm, lam, W, bv, wp2, biasmat, out + OUT0);
    agg_kernel<<<NB * TDIM / 2, 256, 0, stream>>>(x, A, Bm, lam, gt);
    gemm_kernel<<<NCOL / 128, 512, 0, stream>>>(wp2, gt, biasmat, out);
  } else {
    fallback_kernel<<<NB * TDIM, 256, 0, stream>>>(x, A, Bm, lam, W, bv, out);
    copyA_kernel<<<(ACNT + 255) / 256, 256, 0, stream>>>(A, out + OUT0);
  }
}

// Round 5
// 126.771 us; speedup vs baseline: 1.2004x; 1.0063x over previous
//
#include <hip/hip_runtime.h>
#include <hip/hip_bf16.h>
#include <stdint.h>

typedef __bf16 bf16_t;
typedef bf16_t bf16x8 __attribute__((ext_vector_type(8)));
typedef float f32x4 __attribute__((ext_vector_type(4)));

#define DEVI static __device__ __forceinline__

constexpr int NB = 32, CIN = 256, COUT = 256, KNUM = 6, ET = 3, TDIM = 64, VV = 25;
constexpr int KD   = KNUM * CIN;       // 1536 contraction dim (k,ci)
constexpr long OUT0 = (long)NB * COUT * TDIM * VV;  // 13107200 (x_sum elems)
constexpr int ACNT = ET * VV * VV;     // 1875 (A copy)

// workspace layout (gt intermediate eliminated by fusion)
constexpr size_t WP_OFF     = 0;
constexpr size_t WP_BYTES   = (size_t)COUT * KD * 2;        // Wp, bf16 [c][kc]
constexpr size_t BIAS_OFF   = WP_OFF + WP_BYTES;
constexpr size_t BIAS_BYTES = (size_t)NB * VV * COUT * 4;   // bias [n][w][c] f32
constexpr size_t WS_NEED    = BIAS_OFF + BIAS_BYTES;

DEVI unsigned packbf(float lo, float hi) {
  unsigned short a = __builtin_bit_cast(unsigned short, (bf16_t)lo);
  unsigned short b = __builtin_bit_cast(unsigned short, (bf16_t)hi);
  return ((unsigned)b << 16) | (unsigned)a;
}

DEVI void gload16(const void* g, void* l) {
  __builtin_amdgcn_global_load_lds((const __attribute__((address_space(1))) void*)g,
                                   (__attribute__((address_space(3))) void*)l, 16, 0, 0);
}

// ---------------- prep: Wp permute + bias table + A copy ----------------
__global__ __launch_bounds__(256) void prep_kernel(
    const float* __restrict__ A, const float* __restrict__ Bm,
    const float* __restrict__ lam_p, const float* __restrict__ W,
    const float* __restrict__ bvec, bf16_t* __restrict__ wp2,
    float* __restrict__ biasmat, float* __restrict__ outA)
{
  int idx = blockIdx.x * 256 + threadIdx.x;
  constexpr int S1 = COUT * KD;             // 393216
  constexpr int S2 = S1 + NB * VV * COUT;   // +204800
  constexpr int S3 = S2 + ACNT;
  if (idx < S1) {
    // Wp2[c][k*256+ci] = W[ci][k*256+c]
    int c = idx / KD;
    int r = idx - c * KD;
    int k = r >> 8, ci = r & 255;
    wp2[idx] = (bf16_t)W[ci * KD + (k << 8) + c];
  } else if (idx < S2) {
    // bias[n][w][c] = sum_k b[k*256+c] * S[n,k,w],  S = col-sum of M (lam folded)
    int j = idx - S1;
    int c = j & 255;
    int nw = j >> 8;
    int w = nw % VV;
    int n = nw / VV;
    float lam = lam_p[0];
    float s = 0.f;
    for (int k = 0; k < KNUM; ++k) {
      float sk = 0.f;
      if (k < ET) {
        for (int v = 0; v < VV; ++v) sk += A[(k * VV + v) * VV + w];
      } else {
        for (int v = 0; v < VV; ++v) sk += Bm[(((n * ET) + (k - ET)) * VV + v) * VV + w];
        sk *= lam;
      }
      s += bvec[(k << 8) + c] * sk;
    }
    biasmat[j] = s;
  } else if (idx < S3) {
    int j = idx - S2;
    outA[j] = A[j];   // second tuple output: A passthrough
  }
}

// ---------------- fused kernel: out = Wp^T @ agg(x, M), no gt round-trip ----
// Block = (n, 4 t's). Padded col space: col = dt*32 + w (w<25 valid), BN=128.
// Per step (cb 0..3, k 0..5):
//   MFMA#1: Xs[row=dt*64+ci][v] x Ms[k][w][v] -> D, packed/transposed into
//           Bs[col][ci] (pad-72 rows, 2-way banks).
//   As tile (wp2[c][k*256+cb*64+..]) async-staged via global_load_lds with
//   seg-XOR pre-swizzled SOURCE (linear LDS dest, swizzled read) -> no 16-way
//   conflict on the 128B-stride As reads.
//   barrier; 32x MFMA#2 into acc; barrier.
__global__ __launch_bounds__(512, 4) void fused_kernel(
    const float* __restrict__ x, const float* __restrict__ A,
    const float* __restrict__ Bm, const float* __restrict__ lam_p,
    const bf16_t* __restrict__ wp2, const float* __restrict__ biasmat,
    float* __restrict__ out)
{
  __shared__ bf16_t As[256 * 64];        // 32 KB, MFMA#2 A (seg-swizzled src)
  __shared__ bf16_t Bs[128 * 72];        // 18 KB, MFMA#2 B [col=dt*32+w][ci]
  __shared__ bf16_t Xs[256 * 32];        // 16 KB, MFMA#1 A [row=dt*64+ci][v]
  __shared__ bf16_t Ms[KNUM * 32 * 32];  // 12 KB, MFMA#1 B [k][w][v] zero-pad

  const int b = blockIdx.x;
  const int n = b >> 4;                  // 0..31
  const int t0 = (b & 15) << 2;          // t-group of 4
  const int tid = threadIdx.x;
  const int wv = tid >> 6, ln = tid & 63;
  const int lw = ln & 15, lg = ln >> 4;
  const float lam = lam_p[0];

  // stage Ms once (zero-padded w>=25, v>=25)
  for (int i = tid; i < KNUM * 32 * 32; i += 512) {
    int k = i >> 10, w = (i >> 5) & 31, v = i & 31;
    float val = 0.f;
    if (w < VV && v < VV)
      val = (k < ET) ? A[(k * VV + v) * VV + w]
                     : lam * Bm[(((n * ET) + (k - ET)) * VV + v) * VV + w];
    Ms[i] = (bf16_t)val;
  }

  f32x4 acc[4][4] = {};
  const int m_base = (wv >> 1) * 64;
  const int n_base = (wv & 1) * 64;
  const f32x4 z4 = {0.f, 0.f, 0.f, 0.f};

  for (int cb = 0; cb < 4; ++cb) {
    __syncthreads();     // Xs overwrite safe (prior MFMA#1 reads done); Ms ready
    // stage Xs: threads 0..255, ci = tid>>2, dt = tid&3 -> row = dt*64+ci
    if (tid < 256) {
      int ci = tid >> 2, dt = tid & 3;
      const float* xp = x + ((long)(n * CIN + cb * 64 + ci) * TDIM + t0 + dt) * VV;
      float xv[25];
      #pragma unroll
      for (int v = 0; v < VV; ++v) xv[v] = xp[v];
      int row = dt * 64 + ci;
      int sw = (row & 3) ^ ((row >> 2) & 3);
      #pragma unroll
      for (int g = 0; g < 4; ++g) {
        char* base = (char*)Xs + row * 64 + ((g ^ sw) & 3) * 16;
        #pragma unroll
        for (int p = 0; p < 4; ++p) {
          int v0 = g * 8 + p * 2;
          float lo = (v0     < VV) ? xv[v0 < VV ? v0 : 0]     : 0.f;
          float hi = (v0 + 1 < VV) ? xv[v0 + 1 < VV ? v0 + 1 : 0] : 0.f;
          *(unsigned*)(base + p * 4) = packbf(lo, hi);
        }
      }
    }
    __syncthreads();

    for (int k = 0; k < KNUM; ++k) {
      // async-stage As: wp2[c][k*256 + cb*64 + 0..63], source seg pre-XOR'd
      const int kpos = k * 256 + cb * 64;
      #pragma unroll
      for (int q = 0; q < 4; ++q) {
        int it = wv * 256 + q * 64 + ln;          // 0..2047 items of 16B
        int row = it >> 3, seg = it & 7;
        gload16(wp2 + ((long)row * KD + kpos + ((seg ^ (row & 7)) << 3)),
                As + it * 8);
      }
      // MFMA#1: this wave's 32 D-rows (2 row-tiles) x 32 w
      bf16x8 mb0 = *(const bf16x8*)&Ms[(k * 32 + lw) * 32 + (lg << 3)];
      bf16x8 mb1 = *(const bf16x8*)&Ms[(k * 32 + 16 + lw) * 32 + (lg << 3)];
      #pragma unroll
      for (int rt = 0; rt < 2; ++rt) {
        int arow = wv * 32 + rt * 16 + lw;
        int sw = (arow & 3) ^ ((arow >> 2) & 3);
        bf16x8 af = *(const bf16x8*)((const char*)Xs + arow * 64 + ((lg ^ sw) & 3) * 16);
        f32x4 d0 = __builtin_amdgcn_mfma_f32_16x16x32_bf16(af, mb0, z4, 0, 0, 0);
        f32x4 d1 = __builtin_amdgcn_mfma_f32_16x16x32_bf16(af, mb1, z4, 0, 0, 0);
        // lane rows rbase..rbase+3 = same dt, ci0..ci0+3 (dt-major rows)
        int rbase = wv * 32 + rt * 16 + (lg << 2);
        int dt = rbase >> 6, ci0 = rbase & 63;
        char* c0 = (char*)Bs + ((dt * 32 + lw) * 72 + ci0) * 2;
        *(unsigned*)(c0)     = packbf(d0[0], d0[1]);
        *(unsigned*)(c0 + 4) = packbf(d0[2], d0[3]);
        char* c1 = (char*)Bs + ((dt * 32 + 16 + lw) * 72 + ci0) * 2;
        *(unsigned*)(c1)     = packbf(d1[0], d1[1]);
        *(unsigned*)(c1 + 4) = packbf(d1[2], d1[3]);
      }
      __syncthreads();   // drains As vmcnt + Bs lgkm -> both tiles ready

      // MFMA#2: acc += As(256x64) x Bs(128x64)^T fragments
      #pragma unroll
      for (int kk = 0; kk < 2; ++kk) {
        const int seg = lg + kk * 4;
        bf16x8 af2[4], bf2[4];
        #pragma unroll
        for (int i = 0; i < 4; ++i) {
          int row = m_base + i * 16 + lw;
          af2[i] = *(const bf16x8*)((const char*)As + row * 128 + ((seg ^ (row & 7)) * 16));
        }
        #pragma unroll
        for (int j = 0; j < 4; ++j)
          bf2[j] = *(const bf16x8*)&Bs[(n_base + j * 16 + lw) * 72 + kk * 32 + (lg << 3)];
        #pragma unroll
        for (int i = 0; i < 4; ++i)
          #pragma unroll
          for (int j = 0; j < 4; ++j)
            acc[i][j] = __builtin_amdgcn_mfma_f32_16x16x32_bf16(af2[i], bf2[j], acc[i][j], 0, 0, 0);
      }
      __syncthreads();   // all waves done reading As/Bs before next overwrite
    }
  }

  // epilogue: C/D map col=lane&15, row=(lane>>4)*4+reg [m89-verified]
  #pragma unroll
  for (int j = 0; j < 4; ++j) {
    int colb = n_base + j * 16 + lw;         // 0..127
    int dt = colb >> 5, w = colb & 31;
    if (w < VV) {
      float* ob = out + (long)n * 409600 + (t0 + dt) * 25 + w;
      const float* brow = biasmat + (n * 25 + w) * 256;
      #pragma unroll
      for (int i = 0; i < 4; ++i) {
        int mb = m_base + i * 16 + (lg << 2);
        #pragma unroll
        for (int r = 0; r < 4; ++r) {
          int m = mb + r;
          ob[(long)m * 1600] = acc[i][j][r] + brow[m];
        }
      }
    }
  }
}

// ---------------- ws-free fp32 fallback (insurance) ----------------
__global__ __launch_bounds__(256) void fallback_kernel(
    const float* __restrict__ x, const float* __restrict__ A,
    const float* __restrict__ Bm, const float* __restrict__ lam_p,
    const float* __restrict__ W, const float* __restrict__ bvec,
    float* __restrict__ out)
{
  __shared__ __align__(16) float xs[CIN][28];
  __shared__ __align__(16) float Ms[KNUM][VV][28];   // [k][v][w] padded
  const int nt = blockIdx.x;
  const int n = nt >> 6, t = nt & 63;
  const int tid = threadIdx.x;
  const float lam = lam_p[0];

  const float* xp = x + (((long)(n * CIN + tid) * TDIM + t) * VV);
  #pragma unroll
  for (int v = 0; v < VV; ++v) xs[tid][v] = xp[v];
  xs[tid][25] = xs[tid][26] = xs[tid][27] = 0.f;
  for (int i = tid; i < KNUM * VV * VV; i += 256) {
    int k = i / (VV * VV);
    int r = i - k * VV * VV;
    int v = r / VV;
    int w = r - v * VV;
    Ms[k][v][w] = (k < ET) ? A[(k * VV + v) * VV + w]
                           : lam * Bm[(((n * ET) + (k - ET)) * VV + v) * VV + w];
    if (w == 24) { Ms[k][v][25] = Ms[k][v][26] = Ms[k][v][27] = 0.f; }
  }
  __syncthreads();

  float oacc[28] = {};
  for (int k = 0; k < KNUM; ++k) {
    float yv[28];
    float bv = bvec[(k << 8) + tid];
    #pragma unroll
    for (int v = 0; v < 28; ++v) yv[v] = 0.f;
    for (int ci = 0; ci < CIN; ++ci) {
      float wl = W[ci * KD + (k << 8) + tid];
      const f32x4* x4 = (const f32x4*)&xs[ci][0];
      #pragma unroll
      for (int q = 0; q < 7; ++q) {
        f32x4 xv = x4[q];
        yv[q*4+0] += wl*xv[0]; yv[q*4+1] += wl*xv[1];
        yv[q*4+2] += wl*xv[2]; yv[q*4+3] += wl*xv[3];
      }
    }
    #pragma unroll
    for (int v = 0; v < VV; ++v) {
      float yvv = yv[v] + bv;
      const f32x4* m4 = (const f32x4*)&Ms[k][v][0];
      #pragma unroll
      for (int q = 0; q < 7; ++q) {
        f32x4 mv = m4[q];
        oacc[q*4+0] += yvv*mv[0]; oacc[q*4+1] += yvv*mv[1];
        oacc[q*4+2] += yvv*mv[2]; oacc[q*4+3] += yvv*mv[3];
      }
    }
  }
  float* op = out + (((long)(n * COUT + tid) * TDIM + t) * VV);
  #pragma unroll
  for (int w = 0; w < VV; ++w) op[w] = oacc[w];
}

__global__ void copyA_kernel(const float* __restrict__ A, float* __restrict__ outA) {
  int i = blockIdx.x * 256 + threadIdx.x;
  if (i < ACNT) outA[i] = A[i];
}

extern "C" void kernel_launch(void* const* d_in, const int* in_sizes, int n_in,
                              void* d_out, int out_size, void* d_ws, size_t ws_size,
                              hipStream_t stream) {
  const float* x   = (const float*)d_in[0];
  const float* A   = (const float*)d_in[1];
  const float* Bm  = (const float*)d_in[2];
  const float* lam = (const float*)d_in[3];
  const float* W   = (const float*)d_in[4];
  const float* bv  = (const float*)d_in[5];
  float* out = (float*)d_out;

  if (d_ws != nullptr && ws_size >= WS_NEED) {
    bf16_t* wp2     = (bf16_t*)((char*)d_ws + WP_OFF);
    float*  biasmat = (float*)((char*)d_ws + BIAS_OFF);
    constexpr int PREP_ITEMS = COUT * KD + NB * VV * COUT + ACNT;
    prep_kernel<<<(PREP_ITEMS + 255) / 256, 256, 0, stream>>>(A, Bm, lam, W, bv, wp2, biasmat, out + OUT0);
    fused_kernel<<<NB * 16, 512, 0, stream>>>(x, A, Bm, lam, wp2, biasmat, out);
  } else {
    fallback_kernel<<<NB * TDIM, 256, 0, stream>>>(x, A, Bm, lam, W, bv, out);
    copyA_kernel<<<(ACNT + 255) / 256, 256, 0, stream>>>(A, out + OUT0);
  }
}

// Round 6
// 92.200 us; speedup vs baseline: 1.6505x; 1.3750x over previous
//
#include <hip/hip_runtime.h>
#include <hip/hip_bf16.h>
#include <stdint.h>

typedef __bf16 bf16_t;
typedef bf16_t bf16x8 __attribute__((ext_vector_type(8)));
typedef float f32x4 __attribute__((ext_vector_type(4)));

#define DEVI static __device__ __forceinline__

constexpr int NB = 32, CIN = 256, COUT = 256, KNUM = 6, ET = 3, TDIM = 64, VV = 25;
constexpr int KD   = KNUM * CIN;       // 1536 contraction dim (k,ci)
constexpr long OUT0 = (long)NB * COUT * TDIM * VV;  // 13107200 (x_sum elems)
constexpr int ACNT = ET * VV * VV;     // 1875 (A copy)

// wp3: W in fragment-order. 24 steps x 2048 chunks x 16B = 768 KB.
// chunk c = ((s*16 + mi)*2 + kk)*64 + ln ; elems e=0..7:
//   wp3[c*8+e] = W[cb*64 + (lg+4*kk)*8 + e][k*256 + mi*16 + lw]
// where s=cb*6+k, lg=ln>>4, lw=ln&15.
constexpr int NSTEP = 24;              // 4 cb x 6 k
constexpr int WP3_CHUNKS = NSTEP * 2048;
constexpr size_t WP3_BYTES  = (size_t)WP3_CHUNKS * 16;      // 768 KB
constexpr size_t BIAS_OFF   = WP3_BYTES;
constexpr size_t BIAS_BYTES = (size_t)NB * VV * COUT * 4;   // bias [n][w][c] f32
constexpr size_t WS_NEED    = BIAS_OFF + BIAS_BYTES;

DEVI unsigned packbf(float lo, float hi) {
  unsigned short a = __builtin_bit_cast(unsigned short, (bf16_t)lo);
  unsigned short b = __builtin_bit_cast(unsigned short, (bf16_t)hi);
  return ((unsigned)b << 16) | (unsigned)a;
}

// ---------------- prep: wp3 fragment-layout + bias table + A copy ----------
__global__ __launch_bounds__(256) void prep_kernel(
    const float* __restrict__ A, const float* __restrict__ Bm,
    const float* __restrict__ lam_p, const float* __restrict__ W,
    const float* __restrict__ bvec, bf16_t* __restrict__ wp3,
    float* __restrict__ biasmat, float* __restrict__ outA)
{
  int idx = blockIdx.x * 256 + threadIdx.x;
  constexpr int S1 = WP3_CHUNKS;            // 49152 (one 16B chunk per thread)
  constexpr int S2 = S1 + NB * VV * COUT;   // +204800
  constexpr int S3 = S2 + ACNT;
  if (idx < S1) {
    int s  = idx >> 11;
    int r  = idx & 2047;
    int mi = r >> 7;
    int kk = (r >> 6) & 1;
    int ln = r & 63;
    int lg = ln >> 4, lw = ln & 15;
    int cb = s / 6, k = s - cb * 6;
    int cibase = cb * 64 + (lg + 4 * kk) * 8;
    int col = (k << 8) + mi * 16 + lw;
    bf16_t* dst = wp3 + ((long)idx << 3);
    #pragma unroll
    for (int e = 0; e < 8; ++e)
      dst[e] = (bf16_t)W[(cibase + e) * KD + col];
  } else if (idx < S2) {
    // bias[n][w][c] = sum_k b[k*256+c] * S[n,k,w],  S = col-sum of M (lam folded)
    int j = idx - S1;
    int c = j & 255;
    int nw = j >> 8;
    int w = nw % VV;
    int n = nw / VV;
    float lam = lam_p[0];
    float s = 0.f;
    for (int k = 0; k < KNUM; ++k) {
      float sk = 0.f;
      if (k < ET) {
        for (int v = 0; v < VV; ++v) sk += A[(k * VV + v) * VV + w];
      } else {
        for (int v = 0; v < VV; ++v) sk += Bm[(((n * ET) + (k - ET)) * VV + v) * VV + w];
        sk *= lam;
      }
      s += bvec[(k << 8) + c] * sk;
    }
    biasmat[j] = s;
  } else if (idx < S3) {
    int j = idx - S2;
    outA[j] = A[j];   // second tuple output: A passthrough
  }
}

// ---------------- fused kernel: out = Wp^T @ agg(x, M), A-frags from global --
// Block = (n, 4 t's). Per step (cb 0..3, k 0..5):
//   af2 regs <- wp3 (fragment-order, coalesced 16B/lane, L2-hot) [issued early]
//   MFMA#1: Xs x Ms -> packed/transposed into Bs[col][ci] (pad-72)
//   barrier ; 32x MFMA#2 into acc (af2 x Bs) ; barrier.
// No As LDS, no per-step vmcnt(0)-coupled staging.
__global__ __launch_bounds__(512, 2) void fused_kernel(
    const float* __restrict__ x, const float* __restrict__ A,
    const float* __restrict__ Bm, const float* __restrict__ lam_p,
    const bf16_t* __restrict__ wp3, const float* __restrict__ biasmat,
    float* __restrict__ out)
{
  __shared__ bf16_t Bs[128 * 72];        // 18 KB, MFMA#2 B [col=dt*32+w][ci]
  __shared__ bf16_t Xs[256 * 32];        // 16 KB, MFMA#1 A [row=dt*64+ci][v]
  __shared__ bf16_t Ms[KNUM * 32 * 32];  // 12 KB, MFMA#1 B [k][w][v] zero-pad

  const int b = blockIdx.x;
  const int n = b >> 4;                  // 0..31
  const int t0 = (b & 15) << 2;          // t-group of 4
  const int tid = threadIdx.x;
  const int wv = tid >> 6, ln = tid & 63;
  const int lw = ln & 15, lg = ln >> 4;
  const float lam = lam_p[0];

  // stage Ms once (zero-padded w>=25, v>=25)
  for (int i = tid; i < KNUM * 32 * 32; i += 512) {
    int k = i >> 10, w = (i >> 5) & 31, v = i & 31;
    float val = 0.f;
    if (w < VV && v < VV)
      val = (k < ET) ? A[(k * VV + v) * VV + w]
                     : lam * Bm[(((n * ET) + (k - ET)) * VV + v) * VV + w];
    Ms[i] = (bf16_t)val;
  }

  f32x4 acc[4][4] = {};
  const int m_base = (wv >> 1) * 64;
  const int mb4 = (wv >> 1) * 4;         // mi base for A-fragments
  const int n_base = (wv & 1) * 64;
  const f32x4 z4 = {0.f, 0.f, 0.f, 0.f};

  for (int cb = 0; cb < 4; ++cb) {
    __syncthreads();     // Xs overwrite safe (prior step fully barriered)
    // stage Xs: threads 0..255, ci = tid>>2, dt = tid&3 -> row = dt*64+ci
    if (tid < 256) {
      int ci = tid >> 2, dt = tid & 3;
      const float* xp = x + ((long)(n * CIN + cb * 64 + ci) * TDIM + t0 + dt) * VV;
      float xv[25];
      #pragma unroll
      for (int v = 0; v < VV; ++v) xv[v] = xp[v];
      int row = dt * 64 + ci;
      int sw = (row & 3) ^ ((row >> 2) & 3);
      #pragma unroll
      for (int g = 0; g < 4; ++g) {
        char* base = (char*)Xs + row * 64 + ((g ^ sw) & 3) * 16;
        #pragma unroll
        for (int p = 0; p < 4; ++p) {
          int v0 = g * 8 + p * 2;
          float lo = (v0     < VV) ? xv[v0 < VV ? v0 : 0]     : 0.f;
          float hi = (v0 + 1 < VV) ? xv[v0 + 1 < VV ? v0 + 1 : 0] : 0.f;
          *(unsigned*)(base + p * 4) = packbf(lo, hi);
        }
      }
    }
    __syncthreads();

    for (int k = 0; k < KNUM; ++k) {
      const int s = cb * 6 + k;
      // A fragments direct global->VGPR (coalesced: addr = base + ln*16)
      bf16x8 af2[2][4];
      const bf16_t* wpS = wp3 + (((long)s * 2048 + (long)mb4 * 128 + ln) << 3);
      #pragma unroll
      for (int kk = 0; kk < 2; ++kk)
        #pragma unroll
        for (int i = 0; i < 4; ++i)
          af2[kk][i] = *(const bf16x8*)(wpS + ((i * 128 + kk * 64) << 3));

      // MFMA#1: this wave's 32 D-rows (2 row-tiles) x 32 w -> Bs
      bf16x8 mb0 = *(const bf16x8*)&Ms[(k * 32 + lw) * 32 + (lg << 3)];
      bf16x8 mb1 = *(const bf16x8*)&Ms[(k * 32 + 16 + lw) * 32 + (lg << 3)];
      #pragma unroll
      for (int rt = 0; rt < 2; ++rt) {
        int arow = wv * 32 + rt * 16 + lw;
        int sw = (arow & 3) ^ ((arow >> 2) & 3);
        bf16x8 af = *(const bf16x8*)((const char*)Xs + arow * 64 + ((lg ^ sw) & 3) * 16);
        f32x4 d0 = __builtin_amdgcn_mfma_f32_16x16x32_bf16(af, mb0, z4, 0, 0, 0);
        f32x4 d1 = __builtin_amdgcn_mfma_f32_16x16x32_bf16(af, mb1, z4, 0, 0, 0);
        // lane rows rbase..rbase+3 = same dt, ci0..ci0+3 (dt-major rows)
        int rbase = wv * 32 + rt * 16 + (lg << 2);
        int dt = rbase >> 6, ci0 = rbase & 63;
        char* c0 = (char*)Bs + ((dt * 32 + lw) * 72 + ci0) * 2;
        *(unsigned*)(c0)     = packbf(d0[0], d0[1]);
        *(unsigned*)(c0 + 4) = packbf(d0[2], d0[3]);
        char* c1 = (char*)Bs + ((dt * 32 + 16 + lw) * 72 + ci0) * 2;
        *(unsigned*)(c1)     = packbf(d1[0], d1[1]);
        *(unsigned*)(c1 + 4) = packbf(d1[2], d1[3]);
      }
      __syncthreads();   // Bs ready

      // MFMA#2: acc += A-frags x Bs fragments
      #pragma unroll
      for (int kk = 0; kk < 2; ++kk) {
        bf16x8 bf2[4];
        #pragma unroll
        for (int j = 0; j < 4; ++j)
          bf2[j] = *(const bf16x8*)&Bs[(n_base + j * 16 + lw) * 72 + kk * 32 + (lg << 3)];
        #pragma unroll
        for (int i = 0; i < 4; ++i)
          #pragma unroll
          for (int j = 0; j < 4; ++j)
            acc[i][j] = __builtin_amdgcn_mfma_f32_16x16x32_bf16(af2[kk][i], bf2[j], acc[i][j], 0, 0, 0);
      }
      __syncthreads();   // all waves done reading Bs before next overwrite
    }
  }

  // epilogue: C/D map col=lane&15, row=(lane>>4)*4+reg [m89-verified]
  #pragma unroll
  for (int j = 0; j < 4; ++j) {
    int colb = n_base + j * 16 + lw;         // 0..127
    int dt = colb >> 5, w = colb & 31;
    if (w < VV) {
      float* ob = out + (long)n * 409600 + (t0 + dt) * 25 + w;
      const float* brow = biasmat + (n * 25 + w) * 256;
      #pragma unroll
      for (int i = 0; i < 4; ++i) {
        int mb = m_base + i * 16 + (lg << 2);
        #pragma unroll
        for (int r = 0; r < 4; ++r) {
          int m = mb + r;
          ob[(long)m * 1600] = acc[i][j][r] + brow[m];
        }
      }
    }
  }
}

// ---------------- ws-free fp32 fallback (insurance) ----------------
__global__ __launch_bounds__(256) void fallback_kernel(
    const float* __restrict__ x, const float* __restrict__ A,
    const float* __restrict__ Bm, const float* __restrict__ lam_p,
    const float* __restrict__ W, const float* __restrict__ bvec,
    float* __restrict__ out)
{
  __shared__ __align__(16) float xs[CIN][28];
  __shared__ __align__(16) float Ms[KNUM][VV][28];   // [k][v][w] padded
  const int nt = blockIdx.x;
  const int n = nt >> 6, t = nt & 63;
  const int tid = threadIdx.x;
  const float lam = lam_p[0];

  const float* xp = x + (((long)(n * CIN + tid) * TDIM + t) * VV);
  #pragma unroll
  for (int v = 0; v < VV; ++v) xs[tid][v] = xp[v];
  xs[tid][25] = xs[tid][26] = xs[tid][27] = 0.f;
  for (int i = tid; i < KNUM * VV * VV; i += 256) {
    int k = i / (VV * VV);
    int r = i - k * VV * VV;
    int v = r / VV;
    int w = r - v * VV;
    Ms[k][v][w] = (k < ET) ? A[(k * VV + v) * VV + w]
                           : lam * Bm[(((n * ET) + (k - ET)) * VV + v) * VV + w];
    if (w == 24) { Ms[k][v][25] = Ms[k][v][26] = Ms[k][v][27] = 0.f; }
  }
  __syncthreads();

  float oacc[28] = {};
  for (int k = 0; k < KNUM; ++k) {
    float yv[28];
    float bv = bvec[(k << 8) + tid];
    #pragma unroll
    for (int v = 0; v < 28; ++v) yv[v] = 0.f;
    for (int ci = 0; ci < CIN; ++ci) {
      float wl = W[ci * KD + (k << 8) + tid];
      const f32x4* x4 = (const f32x4*)&xs[ci][0];
      #pragma unroll
      for (int q = 0; q < 7; ++q) {
        f32x4 xv = x4[q];
        yv[q*4+0] += wl*xv[0]; yv[q*4+1] += wl*xv[1];
        yv[q*4+2] += wl*xv[2]; yv[q*4+3] += wl*xv[3];
      }
    }
    #pragma unroll
    for (int v = 0; v < VV; ++v) {
      float yvv = yv[v] + bv;
      const f32x4* m4 = (const f32x4*)&Ms[k][v][0];
      #pragma unroll
      for (int q = 0; q < 7; ++q) {
        f32x4 mv = m4[q];
        oacc[q*4+0] += yvv*mv[0]; oacc[q*4+1] += yvv*mv[1];
        oacc[q*4+2] += yvv*mv[2]; oacc[q*4+3] += yvv*mv[3];
      }
    }
  }
  float* op = out + (((long)(n * COUT + tid) * TDIM + t) * VV);
  #pragma unroll
  for (int w = 0; w < VV; ++w) op[w] = oacc[w];
}

__global__ void copyA_kernel(const float* __restrict__ A, float* __restrict__ outA) {
  int i = blockIdx.x * 256 + threadIdx.x;
  if (i < ACNT) outA[i] = A[i];
}

extern "C" void kernel_launch(void* const* d_in, const int* in_sizes, int n_in,
                              void* d_out, int out_size, void* d_ws, size_t ws_size,
                              hipStream_t stream) {
  const float* x   = (const float*)d_in[0];
  const float* A   = (const float*)d_in[1];
  const float* Bm  = (const float*)d_in[2];
  const float* lam = (const float*)d_in[3];
  const float* W   = (const float*)d_in[4];
  const float* bv  = (const float*)d_in[5];
  float* out = (float*)d_out;

  if (d_ws != nullptr && ws_size >= WS_NEED) {
    bf16_t* wp3     = (bf16_t*)d_ws;
    float*  biasmat = (float*)((char*)d_ws + BIAS_OFF);
    constexpr int PREP_ITEMS = WP3_CHUNKS + NB * VV * COUT + ACNT;
    prep_kernel<<<(PREP_ITEMS + 255) / 256, 256, 0, stream>>>(A, Bm, lam, W, bv, wp3, biasmat, out + OUT0);
    fused_kernel<<<NB * 16, 512, 0, stream>>>(x, A, Bm, lam, wp3, biasmat, out);
  } else {
    fallback_kernel<<<NB * TDIM, 256, 0, stream>>>(x, A, Bm, lam, W, bv, out);
    copyA_kernel<<<(ACNT + 255) / 256, 256, 0, stream>>>(A, out + OUT0);
  }
}

// Round 7
// 84.550 us; speedup vs baseline: 1.7998x; 1.0905x over previous
//
#include <hip/hip_runtime.h>
#include <hip/hip_bf16.h>
#include <stdint.h>

typedef __bf16 bf16_t;
typedef bf16_t bf16x8 __attribute__((ext_vector_type(8)));
typedef float f32x4 __attribute__((ext_vector_type(4)));

#define DEVI static __device__ __forceinline__

constexpr int NB = 32, CIN = 256, COUT = 256, KNUM = 6, ET = 3, TDIM = 64, VV = 25;
constexpr int KD   = KNUM * CIN;       // 1536 contraction dim (k,ci)
constexpr long OUT0 = (long)NB * COUT * TDIM * VV;  // 13107200 (x_sum elems)
constexpr int ACNT = ET * VV * VV;     // 1875 (A copy)

// wp3: W in fragment-order. 24 steps x 2048 chunks x 16B = 768 KB.
constexpr int NSTEP = 24;              // 4 cb x 6 k
constexpr int WP3_CHUNKS = NSTEP * 2048;
constexpr size_t WP3_BYTES  = (size_t)WP3_CHUNKS * 16;      // 768 KB
constexpr size_t BIAS_OFF   = WP3_BYTES;
constexpr size_t BIAS_BYTES = (size_t)NB * VV * COUT * 4;   // bias [n][w][c] f32
constexpr size_t WS_NEED    = BIAS_OFF + BIAS_BYTES;

DEVI unsigned packbf(float lo, float hi) {
  unsigned short a = __builtin_bit_cast(unsigned short, (bf16_t)lo);
  unsigned short b = __builtin_bit_cast(unsigned short, (bf16_t)hi);
  return ((unsigned)b << 16) | (unsigned)a;
}

// ---------------- prep: wp3 fragment-layout + bias table + A copy ----------
__global__ __launch_bounds__(256) void prep_kernel(
    const float* __restrict__ A, const float* __restrict__ Bm,
    const float* __restrict__ lam_p, const float* __restrict__ W,
    const float* __restrict__ bvec, bf16_t* __restrict__ wp3,
    float* __restrict__ biasmat, float* __restrict__ outA)
{
  int idx = blockIdx.x * 256 + threadIdx.x;
  constexpr int S1 = WP3_CHUNKS;            // 49152 (one 16B chunk per thread)
  constexpr int S2 = S1 + NB * VV * COUT;   // +204800
  constexpr int S3 = S2 + ACNT;
  if (idx < S1) {
    int s  = idx >> 11;
    int r  = idx & 2047;
    int mi = r >> 7;
    int kk = (r >> 6) & 1;
    int ln = r & 63;
    int lg = ln >> 4, lw = ln & 15;
    int cb = s / 6, k = s - cb * 6;
    int cibase = cb * 64 + (lg + 4 * kk) * 8;
    int col = (k << 8) + mi * 16 + lw;
    bf16_t* dst = wp3 + ((long)idx << 3);
    #pragma unroll
    for (int e = 0; e < 8; ++e)
      dst[e] = (bf16_t)W[(cibase + e) * KD + col];
  } else if (idx < S2) {
    // bias[n][w][c] = sum_k b[k*256+c] * S[n,k,w],  S = col-sum of M (lam folded)
    int j = idx - S1;
    int c = j & 255;
    int nw = j >> 8;
    int w = nw % VV;
    int n = nw / VV;
    float lam = lam_p[0];
    float s = 0.f;
    for (int k = 0; k < KNUM; ++k) {
      float sk = 0.f;
      if (k < ET) {
        for (int v = 0; v < VV; ++v) sk += A[(k * VV + v) * VV + w];
      } else {
        for (int v = 0; v < VV; ++v) sk += Bm[(((n * ET) + (k - ET)) * VV + v) * VV + w];
        sk *= lam;
      }
      s += bvec[(k << 8) + c] * sk;
    }
    biasmat[j] = s;
  } else if (idx < S3) {
    int j = idx - S2;
    outA[j] = A[j];   // second tuple output: A passthrough
  }
}

// ---------------- fused kernel ----------------------------------------------
// Per step (cb,k): af2 <- wp3 (global, frag-order); MFMA#1 Xs x Ms -> Bs[buf]
// (XOR-swizzled, dbuf); ONE barrier; MFMA#2 accum (setprio-wrapped).
__global__ __launch_bounds__(512, 2) void fused_kernel(
    const float* __restrict__ x, const float* __restrict__ A,
    const float* __restrict__ Bm, const float* __restrict__ lam_p,
    const bf16_t* __restrict__ wp3, const float* __restrict__ biasmat,
    float* __restrict__ out)
{
  __shared__ bf16_t Bs[2 * 128 * 64];    // 32 KB dbuf, rows 128B, grp^=(row&7)
  __shared__ bf16_t Xs[256 * 32];        // 16 KB [row=dt*64+ci][v] swizzled
  __shared__ bf16_t Ms[KNUM * 32 * 32];  // 12 KB [k][w][v] swizzled, zero-pad

  const int b = blockIdx.x;
  const int n = b >> 4;                  // 0..31
  const int t0 = (b & 15) << 2;          // t-group of 4
  const int tid = threadIdx.x;
  const int wv = tid >> 6, ln = tid & 63;
  const int lw = ln & 15, lg = ln >> 4;
  const float lam = lam_p[0];

  // stage Ms once: row R=k*32+w (64B), group-XOR sw2=(w&3)^((w>>2)&3)
  for (int i = tid; i < KNUM * 32 * 32; i += 512) {
    int R = i >> 5, v = i & 31;
    int k = i >> 10, w = (i >> 5) & 31;
    float val = 0.f;
    if (w < VV && v < VV)
      val = (k < ET) ? A[(k * VV + v) * VV + w]
                     : lam * Bm[(((n * ET) + (k - ET)) * VV + v) * VV + w];
    int sw2 = (w & 3) ^ ((w >> 2) & 3);
    int byteoff = R * 64 + ((((v >> 3) ^ sw2) & 3) << 4) + ((v & 7) << 1);
    *(bf16_t*)((char*)Ms + byteoff) = (bf16_t)val;
  }

  f32x4 acc[4][4] = {};
  const int m_base = (wv >> 1) * 64;
  const int mb4 = (wv >> 1) * 4;         // mi base for A-fragments
  const int n_base = (wv & 1) * 64;
  const f32x4 z4 = {0.f, 0.f, 0.f, 0.f};
  const int msw2 = (lw & 3) ^ ((lw >> 2) & 3);   // Ms read swizzle (rows lw, lw+16)

  for (int cb = 0; cb < 4; ++cb) {
    // stage Xs for this cb (safe: last Xs reads precede the last step barrier)
    if (tid < 256) {
      int ci = tid >> 2, dt = tid & 3;
      const float* xp = x + ((long)(n * CIN + cb * 64 + ci) * TDIM + t0 + dt) * VV;
      float xv[25];
      #pragma unroll
      for (int v = 0; v < VV; ++v) xv[v] = xp[v];
      int row = dt * 64 + ci;
      int sw = (row & 3) ^ ((row >> 2) & 3);
      #pragma unroll
      for (int g = 0; g < 4; ++g) {
        char* base = (char*)Xs + row * 64 + ((g ^ sw) & 3) * 16;
        #pragma unroll
        for (int p = 0; p < 4; ++p) {
          int v0 = g * 8 + p * 2;
          float lo = (v0     < VV) ? xv[v0 < VV ? v0 : 0]     : 0.f;
          float hi = (v0 + 1 < VV) ? xv[v0 + 1 < VV ? v0 + 1 : 0] : 0.f;
          *(unsigned*)(base + p * 4) = packbf(lo, hi);
        }
      }
    }
    __syncthreads();   // Xs visible; also isolates prior Bs readers

    for (int k = 0; k < KNUM; ++k) {
      const int s = cb * 6 + k;
      const int buf = (s & 1) * (128 * 64);
      // A fragments direct global->VGPR (coalesced 16B/lane, L2-hot)
      bf16x8 af2[2][4];
      const bf16_t* wpS = wp3 + (((long)s * 2048 + (long)mb4 * 128 + ln) << 3);
      #pragma unroll
      for (int kk = 0; kk < 2; ++kk)
        #pragma unroll
        for (int i = 0; i < 4; ++i)
          af2[kk][i] = *(const bf16x8*)(wpS + ((i * 128 + kk * 64) << 3));

      // MFMA#1: Xs x Ms -> Bs[buf]
      bf16x8 mb0 = *(const bf16x8*)((const char*)Ms + (k * 32 + lw) * 64 + (((lg ^ msw2) & 3) << 4));
      bf16x8 mb1 = *(const bf16x8*)((const char*)Ms + (k * 32 + 16 + lw) * 64 + (((lg ^ msw2) & 3) << 4));
      #pragma unroll
      for (int rt = 0; rt < 2; ++rt) {
        int arow = wv * 32 + rt * 16 + lw;
        int sw = (arow & 3) ^ ((arow >> 2) & 3);
        bf16x8 af = *(const bf16x8*)((const char*)Xs + arow * 64 + ((lg ^ sw) & 3) * 16);
        f32x4 d0 = __builtin_amdgcn_mfma_f32_16x16x32_bf16(af, mb0, z4, 0, 0, 0);
        f32x4 d1 = __builtin_amdgcn_mfma_f32_16x16x32_bf16(af, mb1, z4, 0, 0, 0);
        int rbase = wv * 32 + rt * 16 + (lg << 2);
        int dt = rbase >> 6, ci0 = rbase & 63;
        int r0 = dt * 32 + lw;
        int g0 = ((ci0 >> 3) ^ (r0 & 7)) & 7;
        char* c0 = (char*)(Bs + buf) + r0 * 128 + (g0 << 4) + ((ci0 << 1) & 15);
        *(unsigned*)(c0)     = packbf(d0[0], d0[1]);
        *(unsigned*)(c0 + 4) = packbf(d0[2], d0[3]);
        int r1 = r0 + 16;     // same &7 -> same group XOR
        char* c1 = (char*)(Bs + buf) + r1 * 128 + (g0 << 4) + ((ci0 << 1) & 15);
        *(unsigned*)(c1)     = packbf(d1[0], d1[1]);
        *(unsigned*)(c1 + 4) = packbf(d1[2], d1[3]);
      }
      __syncthreads();   // Bs[buf] ready (single barrier per step; dbuf)

      // MFMA#2: acc += af2 x Bs[buf]
      __builtin_amdgcn_s_setprio(1);
      #pragma unroll
      for (int kk = 0; kk < 2; ++kk) {
        bf16x8 bf2[4];
        #pragma unroll
        for (int j = 0; j < 4; ++j) {
          int rr = n_base + j * 16 + lw;
          int gg = ((kk * 4 + lg) ^ (rr & 7)) & 7;
          bf2[j] = *(const bf16x8*)((const char*)(Bs + buf) + rr * 128 + (gg << 4));
        }
        #pragma unroll
        for (int i = 0; i < 4; ++i)
          #pragma unroll
          for (int j = 0; j < 4; ++j)
            acc[i][j] = __builtin_amdgcn_mfma_f32_16x16x32_bf16(af2[kk][i], bf2[j], acc[i][j], 0, 0, 0);
      }
      __builtin_amdgcn_s_setprio(0);
    }
  }

  // epilogue: C/D map col=lane&15, row=(lane>>4)*4+reg [m89-verified]
  #pragma unroll
  for (int j = 0; j < 4; ++j) {
    int colb = n_base + j * 16 + lw;         // 0..127
    int dt = colb >> 5, w = colb & 31;
    if (w < VV) {
      float* ob = out + (long)n * 409600 + (t0 + dt) * 25 + w;
      const float* brow = biasmat + (n * 25 + w) * 256;
      #pragma unroll
      for (int i = 0; i < 4; ++i) {
        int mb = m_base + i * 16 + (lg << 2);
        #pragma unroll
        for (int r = 0; r < 4; ++r) {
          int m = mb + r;
          ob[(long)m * 1600] = acc[i][j][r] + brow[m];
        }
      }
    }
  }
}

// ---------------- ws-free fp32 fallback (insurance) ----------------
__global__ __launch_bounds__(256) void fallback_kernel(
    const float* __restrict__ x, const float* __restrict__ A,
    const float* __restrict__ Bm, const float* __restrict__ lam_p,
    const float* __restrict__ W, const float* __restrict__ bvec,
    float* __restrict__ out)
{
  __shared__ __align__(16) float xs[CIN][28];
  __shared__ __align__(16) float Ms[KNUM][VV][28];   // [k][v][w] padded
  const int nt = blockIdx.x;
  const int n = nt >> 6, t = nt & 63;
  const int tid = threadIdx.x;
  const float lam = lam_p[0];

  const float* xp = x + (((long)(n * CIN + tid) * TDIM + t) * VV);
  #pragma unroll
  for (int v = 0; v < VV; ++v) xs[tid][v] = xp[v];
  xs[tid][25] = xs[tid][26] = xs[tid][27] = 0.f;
  for (int i = tid; i < KNUM * VV * VV; i += 256) {
    int k = i / (VV * VV);
    int r = i - k * VV * VV;
    int v = r / VV;
    int w = r - v * VV;
    Ms[k][v][w] = (k < ET) ? A[(k * VV + v) * VV + w]
                           : lam * Bm[(((n * ET) + (k - ET)) * VV + v) * VV + w];
    if (w == 24) { Ms[k][v][25] = Ms[k][v][26] = Ms[k][v][27] = 0.f; }
  }
  __syncthreads();

  float oacc[28] = {};
  for (int k = 0; k < KNUM; ++k) {
    float yv[28];
    float bv = bvec[(k << 8) + tid];
    #pragma unroll
    for (int v = 0; v < 28; ++v) yv[v] = 0.f;
    for (int ci = 0; ci < CIN; ++ci) {
      float wl = W[ci * KD + (k << 8) + tid];
      const f32x4* x4 = (const f32x4*)&xs[ci][0];
      #pragma unroll
      for (int q = 0; q < 7; ++q) {
        f32x4 xv = x4[q];
        yv[q*4+0] += wl*xv[0]; yv[q*4+1] += wl*xv[1];
        yv[q*4+2] += wl*xv[2]; yv[q*4+3] += wl*xv[3];
      }
    }
    #pragma unroll
    for (int v = 0; v < VV; ++v) {
      float yvv = yv[v] + bv;
      const f32x4* m4 = (const f32x4*)&Ms[k][v][0];
      #pragma unroll
      for (int q = 0; q < 7; ++q) {
        f32x4 mv = m4[q];
        oacc[q*4+0] += yvv*mv[0]; oacc[q*4+1] += yvv*mv[1];
        oacc[q*4+2] += yvv*mv[2]; oacc[q*4+3] += yvv*mv[3];
      }
    }
  }
  float* op = out + (((long)(n * COUT + tid) * TDIM + t) * VV);
  #pragma unroll
  for (int w = 0; w < VV; ++w) op[w] = oacc[w];
}

__global__ void copyA_kernel(const float* __restrict__ A, float* __restrict__ outA) {
  int i = blockIdx.x * 256 + threadIdx.x;
  if (i < ACNT) outA[i] = A[i];
}

extern "C" void kernel_launch(void* const* d_in, const int* in_sizes, int n_in,
                              void* d_out, int out_size, void* d_ws, size_t ws_size,
                              hipStream_t stream) {
  const float* x   = (const float*)d_in[0];
  const float* A   = (const float*)d_in[1];
  const float* Bm  = (const float*)d_in[2];
  const float* lam = (const float*)d_in[3];
  const float* W   = (const float*)d_in[4];
  const float* bv  = (const float*)d_in[5];
  float* out = (float*)d_out;

  if (d_ws != nullptr && ws_size >= WS_NEED) {
    bf16_t* wp3     = (bf16_t*)d_ws;
    float*  biasmat = (float*)((char*)d_ws + BIAS_OFF);
    constexpr int PREP_ITEMS = WP3_CHUNKS + NB * VV * COUT + ACNT;
    prep_kernel<<<(PREP_ITEMS + 255) / 256, 256, 0, stream>>>(A, Bm, lam, W, bv, wp3, biasmat, out + OUT0);
    fused_kernel<<<NB * 16, 512, 0, stream>>>(x, A, Bm, lam, wp3, biasmat, out);
  } else {
    fallback_kernel<<<NB * TDIM, 256, 0, stream>>>(x, A, Bm, lam, W, bv, out);
    copyA_kernel<<<(ACNT + 255) / 256, 256, 0, stream>>>(A, out + OUT0);
  }
}